// Round 5
// baseline (236.338 us; speedup 1.0000x reference)
//
#include <hip/hip_runtime.h>

#define DIM 512
#define WAVE 64
#define WPB 4                      // waves per block
#define RSER 8                     // rows processed serially per wave
#define BLOCK (WAVE * WPB)
#define ROWS_PER_BLOCK (WPB * RSER)  // 32

// ---- DS-free 64-lane butterflies (proven in round 4: correct, ~10 VALU) ----
#define DPPF(x, ctrl) __int_as_float(__builtin_amdgcn_update_dpp( \
    __float_as_int(x), __float_as_int(x), (ctrl), 0xf, 0xf, false))

__device__ __forceinline__ float red16_sum(float x) {
    x += DPPF(x, 0xB1);   // quad_perm xor1
    x += DPPF(x, 0x4E);   // quad_perm xor2
    x += DPPF(x, 0x124);  // row_ror:4
    x += DPPF(x, 0x128);  // row_ror:8
    return x;
}
__device__ __forceinline__ float red16_max(float x) {
    x = fmaxf(x, DPPF(x, 0xB1));
    x = fmaxf(x, DPPF(x, 0x4E));
    x = fmaxf(x, DPPF(x, 0x124));
    x = fmaxf(x, DPPF(x, 0x128));
    return x;
}
__device__ __forceinline__ float xswap16_sum(float x) {
    float t = x, u = x;
    asm("" : "+v"(u));
    asm("v_permlane16_swap_b32 %0, %1" : "+v"(t), "+v"(u));
    return t + u;
}
__device__ __forceinline__ float xswap32_sum(float x) {
    float t = x, u = x;
    asm("" : "+v"(u));
    asm("v_permlane32_swap_b32 %0, %1" : "+v"(t), "+v"(u));
    return t + u;
}
__device__ __forceinline__ float xswap16_max(float x) {
    float t = x, u = x;
    asm("" : "+v"(u));
    asm("v_permlane16_swap_b32 %0, %1" : "+v"(t), "+v"(u));
    return fmaxf(t, u);
}
__device__ __forceinline__ float xswap32_max(float x) {
    float t = x, u = x;
    asm("" : "+v"(u));
    asm("v_permlane32_swap_b32 %0, %1" : "+v"(t), "+v"(u));
    return fmaxf(t, u);
}
__device__ __forceinline__ float allred_sum(float x) {
    return xswap32_sum(xswap16_sum(red16_sum(x)));
}
__device__ __forceinline__ float allred_max(float x) {
    return xswap32_max(xswap16_max(red16_max(x)));
}

// ---- async global->LDS DMA (16B/lane, wave-uniform LDS base + lane*16) -----
__device__ __forceinline__ void gload_lds16(const float* g, float* l) {
    __builtin_amdgcn_global_load_lds(
        (const __attribute__((address_space(1))) void*)g,
        (__attribute__((address_space(3))) void*)l, 16, 0, 0);
}
// one 2KiB row = two DMA instructions (1 KiB each: 64 lanes x 16B)
__device__ __forceinline__ void pf_row(const float* grow, float* ldsrow, int lane) {
    gload_lds16(grow + 4 * lane,       ldsrow);
    gload_lds16(grow + 4 * lane + 256, ldsrow + 256);
}

#define WAITVM(n)  asm volatile("s_waitcnt vmcnt(" #n ")" ::: "memory")
#define WAITLGKM0  asm volatile("s_waitcnt lgkmcnt(0)" ::: "memory")

__global__ __launch_bounds__(BLOCK) void sparsemax_kernel(
    const float* __restrict__ x, float* __restrict__ out, int batch) {
    // Latency-bound diagnosis (r4: VALU 32%, HBM 32%, occ 60%): waves had only
    // 2 KiB in flight then a ~1000-cyc serial Michelot chain -> ~14 KiB/CU
    // outstanding vs ~22 KiB needed for BW saturation. Fix: each wave streams
    // 8 rows, double-buffered in LDS via global_load_lds (depth-2 prefetch),
    // counted vmcnt waits (never 0 -> stores stay in flight). Per-lane live
    // set stays at the proven z[8].
    __shared__ float buf[WPB][2][DIM];   // 16 KiB/block
    const int wid  = threadIdx.x >> 6;
    const int lane = threadIdx.x & 63;
    const long rowBase = ((long)blockIdx.x * WPB + wid) * RSER;
    if (rowBase >= batch) return;
    const float* xb  = x   + rowBase * DIM;
    float*       ob  = out + rowBase * DIM;
    float* s0 = &buf[wid][0][0];
    float* s1 = &buf[wid][1][0];

    // prologue: rows 0,1 in flight immediately
    pf_row(xb,       s0, lane);
    pf_row(xb + DIM, s1, lane);

#pragma unroll
    for (int r = 0; r < RSER; ++r) {
        float* slot = (r & 1) ? s1 : s0;
        // vmcnt retires in issue order: these leave stores (and the younger
        // prefetch) outstanding while guaranteeing THIS slot's 2 loads landed.
        if (r == 0)      WAITVM(2);
        else if (r == 1) WAITVM(4);
        else             WAITVM(6);

        const float4* bp = reinterpret_cast<const float4*>(slot);
        float4 a = bp[lane];
        float4 b = bp[lane + WAVE];
        WAITLGKM0;  // slot fully read -> safe to overwrite with next DMA

        // refill this slot with row r+2 (clamped: tail re-reads last row, L2-hit)
        const int pr = (r + 2 < RSER) ? r + 2 : RSER - 1;
        pf_row(xb + (long)pr * DIM, slot, lane);

        float z[8] = {a.x, a.y, a.z, a.w, b.x, b.y, b.z, b.w};

        // tau0 = max - 1 (valid lower bound: p_max <= 1)
        float m = fmaxf(fmaxf(fmaxf(z[0], z[1]), fmaxf(z[2], z[3])),
                        fmaxf(fmaxf(z[4], z[5]), fmaxf(z[6], z[7])));
        m = allred_max(m);
        float tau = m - 1.0f;

        // Michelot fixed point: tau' = (S-1)/K over {z > tau}; sets shrink
        // from a lower bound; K stable <=> fixed point (exact, finite).
        int kprev = 0;
        for (int it = 0; it < 32; ++it) {
            float S = 0.f;
            int   K = 0;
#pragma unroll
            for (int j = 0; j < 8; ++j) {
                const bool in = z[j] > tau;
                S += in ? z[j] : 0.f;
                K += (int)__popcll(__ballot(in));
            }
            S = allred_sum(S);
            if (K == kprev) break;  // wave-uniform
            kprev = K;
            tau = (S - 1.0f) * __builtin_amdgcn_rcpf((float)K);  // K >= 1
        }

        // epilogue: out = max(0, z - tau); stores fly, no wait needed
        float4 oa, ov;
        oa.x = fmaxf(0.f, z[0] - tau);
        oa.y = fmaxf(0.f, z[1] - tau);
        oa.z = fmaxf(0.f, z[2] - tau);
        oa.w = fmaxf(0.f, z[3] - tau);
        ov.x = fmaxf(0.f, z[4] - tau);
        ov.y = fmaxf(0.f, z[5] - tau);
        ov.z = fmaxf(0.f, z[6] - tau);
        ov.w = fmaxf(0.f, z[7] - tau);
        float4* orow = reinterpret_cast<float4*>(ob + (long)r * DIM);
        orow[lane]        = oa;
        orow[lane + WAVE] = ov;
    }
}

extern "C" void kernel_launch(void* const* d_in, const int* in_sizes, int n_in,
                              void* d_out, int out_size, void* d_ws, size_t ws_size,
                              hipStream_t stream) {
    const float* x = (const float*)d_in[0];
    float* out     = (float*)d_out;
    const int batch = in_sizes[0] / DIM;  // 65536
    const int grid  = (batch + ROWS_PER_BLOCK - 1) / ROWS_PER_BLOCK;  // 2048
    sparsemax_kernel<<<grid, BLOCK, 0, stream>>>(x, out, batch);
}

// Round 7
// 227.414 us; speedup vs baseline: 1.0392x; 1.0392x over previous
//
#include <hip/hip_runtime.h>

#define DIM 512
#define WAVE 64
#define WPB 4
#define BLOCK (WAVE * WPB)

typedef float vfloat4 __attribute__((ext_vector_type(4)));  // builtin-compatible

// ---- DS-free 64-lane butterflies (proven r4: correct, ~10 VALU, no LDS) ----
#define DPPF(x, ctrl) __int_as_float(__builtin_amdgcn_update_dpp( \
    __float_as_int(x), __float_as_int(x), (ctrl), 0xf, 0xf, false))

__device__ __forceinline__ float red16_sum(float x) {
    x += DPPF(x, 0xB1);   // quad_perm xor1
    x += DPPF(x, 0x4E);   // quad_perm xor2
    x += DPPF(x, 0x124);  // row_ror:4
    x += DPPF(x, 0x128);  // row_ror:8
    return x;
}
__device__ __forceinline__ float red16_max(float x) {
    x = fmaxf(x, DPPF(x, 0xB1));
    x = fmaxf(x, DPPF(x, 0x4E));
    x = fmaxf(x, DPPF(x, 0x124));
    x = fmaxf(x, DPPF(x, 0x128));
    return x;
}
__device__ __forceinline__ float xswap16_sum(float x) {
    float t = x, u = x;
    asm("" : "+v"(u));
    asm("v_permlane16_swap_b32 %0, %1" : "+v"(t), "+v"(u));
    return t + u;
}
__device__ __forceinline__ float xswap32_sum(float x) {
    float t = x, u = x;
    asm("" : "+v"(u));
    asm("v_permlane32_swap_b32 %0, %1" : "+v"(t), "+v"(u));
    return t + u;
}
__device__ __forceinline__ float xswap16_max(float x) {
    float t = x, u = x;
    asm("" : "+v"(u));
    asm("v_permlane16_swap_b32 %0, %1" : "+v"(t), "+v"(u));
    return fmaxf(t, u);
}
__device__ __forceinline__ float xswap32_max(float x) {
    float t = x, u = x;
    asm("" : "+v"(u));
    asm("v_permlane32_swap_b32 %0, %1" : "+v"(t), "+v"(u));
    return fmaxf(t, u);
}
__device__ __forceinline__ float allred_sum(float x) {
    return xswap32_sum(xswap16_sum(red16_sum(x)));
}
__device__ __forceinline__ float allred_max(float x) {
    return xswap32_max(xswap16_max(red16_max(x)));
}

__global__ __launch_bounds__(BLOCK) void sparsemax_kernel(
    const float* __restrict__ x, float* __restrict__ out, int batch) {
    // Round-4 structure (best measured), single change: NON-TEMPORAL stores.
    // Theory: WRITE_SIZE=128MiB of never-re-read output was write-allocating
    // through L2/L3, evicting half the (128MiB, L3-fitting) input each bench
    // iteration -> FETCH_SIZE=64MiB of avoidable HBM re-fetch + queue
    // pressure. nt stores bypass cache allocation; input stays L3-resident.
    const int row  = blockIdx.x * WPB + (threadIdx.x >> 6);
    const int lane = threadIdx.x & 63;
    if (row >= batch) return;

    const float4* xr = reinterpret_cast<const float4*>(x) + (size_t)row * (DIM / 4);
    float4 a = xr[lane];
    float4 b = xr[lane + WAVE];
    float z[8] = {a.x, a.y, a.z, a.w, b.x, b.y, b.z, b.w};

    // ---- tau0 = max - 1 (valid lower bound: p_max <= 1)
    float m = fmaxf(fmaxf(fmaxf(z[0], z[1]), fmaxf(z[2], z[3])),
                    fmaxf(fmaxf(z[4], z[5]), fmaxf(z[6], z[7])));
    m = allred_max(m);
    float tau = m - 1.0f;

    // ---- Michelot fixed point: tau' = (S-1)/K over {z > tau}; sets nested &
    // shrinking from a lower bound, K stable <=> fixed point (exact, finite).
    int kprev = 0;
    for (int it = 0; it < 32; ++it) {
        float S = 0.f;
        int   K = 0;
#pragma unroll
        for (int j = 0; j < 8; ++j) {
            const bool in = z[j] > tau;
            S += in ? z[j] : 0.f;
            K += (int)__popcll(__ballot(in));
        }
        S = allred_sum(S);
        if (K == kprev) break;  // wave-uniform
        kprev = K;
        tau = (S - 1.0f) * __builtin_amdgcn_rcpf((float)K);  // K >= 1 always
    }

    // ---- epilogue: out = max(0, z - tau), nt stores (bypass L2/L3 allocate)
    vfloat4 oa, ob;
    oa.x = fmaxf(0.f, z[0] - tau);
    oa.y = fmaxf(0.f, z[1] - tau);
    oa.z = fmaxf(0.f, z[2] - tau);
    oa.w = fmaxf(0.f, z[3] - tau);
    ob.x = fmaxf(0.f, z[4] - tau);
    ob.y = fmaxf(0.f, z[5] - tau);
    ob.z = fmaxf(0.f, z[6] - tau);
    ob.w = fmaxf(0.f, z[7] - tau);
    vfloat4* orow = reinterpret_cast<vfloat4*>(out) + (size_t)row * (DIM / 4);
    __builtin_nontemporal_store(oa, &orow[lane]);
    __builtin_nontemporal_store(ob, &orow[lane + WAVE]);
}

extern "C" void kernel_launch(void* const* d_in, const int* in_sizes, int n_in,
                              void* d_out, int out_size, void* d_ws, size_t ws_size,
                              hipStream_t stream) {
    const float* x = (const float*)d_in[0];
    float* out     = (float*)d_out;
    const int batch = in_sizes[0] / DIM;  // 65536
    const int grid  = (batch + WPB - 1) / WPB;
    sparsemax_kernel<<<grid, BLOCK, 0, stream>>>(x, out, batch);
}

// Round 8
// 224.182 us; speedup vs baseline: 1.0542x; 1.0144x over previous
//
#include <hip/hip_runtime.h>

#define DIM 512
#define WAVE 64
#define WPB 4
#define BLOCK (WAVE * WPB)

typedef float vfloat4 __attribute__((ext_vector_type(4)));

// ---- non-rematerializable 16B load: inline-asm def cannot be re-executed ---
// Every prior round reported VGPR_Count 12-24 with 8-32 floats/lane live ->
// the backend was rematerializing the (pure, __restrict__) loads INSIDE the
// Michelot loop: ~6-7 x 2KiB/wave L2 round-trips per row, the invariant
// ~78-86us floor. An inline-asm load is opaque to remat/CSE: the result MUST
// stay register-resident.
__device__ __forceinline__ vfloat4 ga_load16(const float* p) {
    vfloat4 r;
    asm volatile("global_load_dwordx4 %0, %1, off" : "=v"(r) : "v"(p));
    return r;
}

// ---- DS-free 64-lane butterflies (r4: correct, ~10 VALU, no LDS) -----------
#define DPPF(x, ctrl) __int_as_float(__builtin_amdgcn_update_dpp( \
    __float_as_int(x), __float_as_int(x), (ctrl), 0xf, 0xf, false))

__device__ __forceinline__ float red16_sum(float x) {
    x += DPPF(x, 0xB1);   // quad_perm xor1
    x += DPPF(x, 0x4E);   // quad_perm xor2
    x += DPPF(x, 0x124);  // row_ror:4
    x += DPPF(x, 0x128);  // row_ror:8
    return x;
}
__device__ __forceinline__ float red16_max(float x) {
    x = fmaxf(x, DPPF(x, 0xB1));
    x = fmaxf(x, DPPF(x, 0x4E));
    x = fmaxf(x, DPPF(x, 0x124));
    x = fmaxf(x, DPPF(x, 0x128));
    return x;
}
__device__ __forceinline__ float xswap16_sum(float x) {
    float t = x, u = x;
    asm("" : "+v"(u));
    asm("v_permlane16_swap_b32 %0, %1" : "+v"(t), "+v"(u));
    return t + u;
}
__device__ __forceinline__ float xswap32_sum(float x) {
    float t = x, u = x;
    asm("" : "+v"(u));
    asm("v_permlane32_swap_b32 %0, %1" : "+v"(t), "+v"(u));
    return t + u;
}
__device__ __forceinline__ float xswap16_max(float x) {
    float t = x, u = x;
    asm("" : "+v"(u));
    asm("v_permlane16_swap_b32 %0, %1" : "+v"(t), "+v"(u));
    return fmaxf(t, u);
}
__device__ __forceinline__ float xswap32_max(float x) {
    float t = x, u = x;
    asm("" : "+v"(u));
    asm("v_permlane32_swap_b32 %0, %1" : "+v"(t), "+v"(u));
    return fmaxf(t, u);
}
__device__ __forceinline__ float allred_sum(float x) {
    return xswap32_sum(xswap16_sum(red16_sum(x)));
}
__device__ __forceinline__ float allred_max(float x) {
    return xswap32_max(xswap16_max(red16_max(x)));
}

__global__ __launch_bounds__(BLOCK) void sparsemax_kernel(
    const float* __restrict__ x, float* __restrict__ out, int batch) {
    const int row  = blockIdx.x * WPB + (threadIdx.x >> 6);
    const int lane = threadIdx.x & 63;
    if (row >= batch) return;

    const float* xr = x + (size_t)row * DIM;
    // asm loads: defs are opaque -> guaranteed register-resident across loop
    vfloat4 a = ga_load16(xr + 4 * lane);
    vfloat4 b = ga_load16(xr + 4 * lane + 256);
    // wait, with a/b as in-outs: consumers are data-ordered AFTER the wait
    // (rule #18: a bare waitcnt can be hoisted past by register-only ops)
    asm volatile("s_waitcnt vmcnt(0)" : "+v"(a), "+v"(b) :: "memory");

    float z[8] = {a.x, a.y, a.z, a.w, b.x, b.y, b.z, b.w};

    // ---- tau0 = max - 1 (valid lower bound: p_max <= 1)
    float m = fmaxf(fmaxf(fmaxf(z[0], z[1]), fmaxf(z[2], z[3])),
                    fmaxf(fmaxf(z[4], z[5]), fmaxf(z[6], z[7])));
    m = allred_max(m);
    float tau = m - 1.0f;

    // ---- Michelot fixed point: tau' = (S-1)/K over {z > tau}; sets nested &
    // shrinking from a lower bound, K stable <=> fixed point (exact, finite).
    int kprev = 0;
    for (int it = 0; it < 32; ++it) {
        float S = 0.f;
        int   K = 0;
#pragma unroll
        for (int j = 0; j < 8; ++j) {
            const bool in = z[j] > tau;
            S += in ? z[j] : 0.f;
            K += (int)__popcll(__ballot(in));
        }
        S = allred_sum(S);
        if (K == kprev) break;  // wave-uniform
        kprev = K;
        tau = (S - 1.0f) * __builtin_amdgcn_rcpf((float)K);  // K >= 1 always
    }

    // ---- epilogue: out = max(0, z - tau)
    float4 oa, ob;
    oa.x = fmaxf(0.f, z[0] - tau);
    oa.y = fmaxf(0.f, z[1] - tau);
    oa.z = fmaxf(0.f, z[2] - tau);
    oa.w = fmaxf(0.f, z[3] - tau);
    ob.x = fmaxf(0.f, z[4] - tau);
    ob.y = fmaxf(0.f, z[5] - tau);
    ob.z = fmaxf(0.f, z[6] - tau);
    ob.w = fmaxf(0.f, z[7] - tau);
    float4* orow = reinterpret_cast<float4*>(out) + (size_t)row * (DIM / 4);
    orow[lane]        = oa;
    orow[lane + WAVE] = ob;
}

extern "C" void kernel_launch(void* const* d_in, const int* in_sizes, int n_in,
                              void* d_out, int out_size, void* d_ws, size_t ws_size,
                              hipStream_t stream) {
    const float* x = (const float*)d_in[0];
    float* out     = (float*)d_out;
    const int batch = in_sizes[0] / DIM;  // 65536
    const int grid  = (batch + WPB - 1) / WPB;
    sparsemax_kernel<<<grid, BLOCK, 0, stream>>>(x, out, batch);
}